// Round 1
// baseline (282.823 us; speedup 1.0000x reference)
//
#include <hip/hip_runtime.h>
#include <math.h>

#define BATCH 32
#define LEN   2048
#define HID   128
#define SSM   256

// ---------------------------------------------------------------------------
// K0: parameter projection + eigenvalue. lam[0..255]=re, lam[256..511]=im.
// ---------------------------------------------------------------------------
__global__ void k0_params(const float* __restrict__ A, const float* __restrict__ G,
                          const float* __restrict__ steps, float* __restrict__ lam) {
    int p = threadIdx.x;
    if (p < SSM) {
        float stp   = 1.f / (1.f + expf(-steps[p]));
        float g     = fmaxf(G[p], 0.f);
        float denom = fmaxf(stp * stp, 1e-6f);
        float s     = stp * g;
        float base  = sqrtf(fmaxf(1.f + s, 1e-6f));
        float alow  = (2.f + s - 2.f * base) / denom;
        float ahigh = (2.f + s + 2.f * base) / denom;
        float a     = alow + fmaxf(A[p] - alow, 0.f) - fmaxf(A[p] - ahigh, 0.f);
        float S     = 1.f / (1.f + stp * g);
        float T     = S + 1.f - stp * stp * S * a;
        lam[p]       = 0.5f * T;
        lam[SSM + p] = sqrtf(fmaxf(S - 0.25f * T * T, 0.f));
    }
}

// ---------------------------------------------------------------------------
// K1: bu[b][p][l] (re,im planes) = sum_h u[b][l][h] * B[p][h][{0,1}]
// Tile: 64 p x 128 l per block, K chunks of 32.
// grid (16,4,32), block 256. Thread tile: 4p x 8l, both complex components.
// ---------------------------------------------------------------------------
__global__ __launch_bounds__(256) void k1_bu(const float* __restrict__ u,
                                             const float* __restrict__ B,
                                             float* __restrict__ bure,
                                             float* __restrict__ buim) {
    __shared__ float sB[2][64][33];                 // [comp][p][k]
    __shared__ __align__(16) float sU[32][128];     // [k][l]
    int tid = threadIdx.x;
    int l0  = blockIdx.x * 128;
    int p0  = blockIdx.y * 64;
    int b   = blockIdx.z;
    int lg  = tid & 15;       // l-group: 8 l each
    int pg  = tid >> 4;       // p-group: 4 p each

    float accr[4][8], acci[4][8];
#pragma unroll
    for (int i = 0; i < 4; ++i)
#pragma unroll
        for (int j = 0; j < 8; ++j) { accr[i][j] = 0.f; acci[i][j] = 0.f; }

    const float* ub = u + (size_t)b * LEN * HID;

    for (int kc = 0; kc < HID; kc += 32) {
        // stage B tile: 64p x 32h, both comps (interleaved re/im -> float4 = 2 h)
#pragma unroll
        for (int i = 0; i < 4; ++i) {
            int idx = tid + 256 * i;          // 0..1023
            int p   = idx >> 4;               // 0..63
            int hp  = idx & 15;               // h = kc + 2*hp
            float4 v = *(const float4*)&B[(size_t)((p0 + p) * HID + kc + hp * 2) * 2];
            sB[0][p][hp * 2]     = v.x;
            sB[1][p][hp * 2]     = v.y;
            sB[0][p][hp * 2 + 1] = v.z;
            sB[1][p][hp * 2 + 1] = v.w;
        }
        // stage U tile transposed: sU[k][l], 128l x 32h
#pragma unroll
        for (int i = 0; i < 4; ++i) {
            int idx = tid + 256 * i;          // 0..1023
            int l   = idx >> 3;               // 0..127
            int hq  = idx & 7;                // h = kc + 4*hq
            float4 v = *(const float4*)&ub[(size_t)(l0 + l) * HID + kc + hq * 4];
            sU[hq * 4 + 0][l] = v.x;
            sU[hq * 4 + 1][l] = v.y;
            sU[hq * 4 + 2][l] = v.z;
            sU[hq * 4 + 3][l] = v.w;
        }
        __syncthreads();
#pragma unroll
        for (int k = 0; k < 32; ++k) {
            float4 u0 = *(const float4*)&sU[k][lg * 8];
            float4 u1 = *(const float4*)&sU[k][lg * 8 + 4];
            float uu[8] = {u0.x, u0.y, u0.z, u0.w, u1.x, u1.y, u1.z, u1.w};
#pragma unroll
            for (int i = 0; i < 4; ++i) {
                float br = sB[0][pg * 4 + i][k];
                float bi = sB[1][pg * 4 + i][k];
#pragma unroll
                for (int j = 0; j < 8; ++j) {
                    accr[i][j] = fmaf(br, uu[j], accr[i][j]);
                    acci[i][j] = fmaf(bi, uu[j], acci[i][j]);
                }
            }
        }
        __syncthreads();
    }
#pragma unroll
    for (int i = 0; i < 4; ++i) {
        size_t row = ((size_t)(b * SSM + p0 + pg * 4 + i)) * LEN + l0 + lg * 8;
        *(float4*)&bure[row]     = make_float4(accr[i][0], accr[i][1], accr[i][2], accr[i][3]);
        *(float4*)&bure[row + 4] = make_float4(accr[i][4], accr[i][5], accr[i][6], accr[i][7]);
        *(float4*)&buim[row]     = make_float4(acci[i][0], acci[i][1], acci[i][2], acci[i][3]);
        *(float4*)&buim[row + 4] = make_float4(acci[i][4], acci[i][5], acci[i][6], acci[i][7]);
    }
}

// ---------------------------------------------------------------------------
// K2: in-place inclusive scan x_k = lam*x_{k-1} + bu_k along l (2048) for each
// (b,p). One block per (b,p); 256 threads x 8 elements. Wave-level
// Hillis-Steele on chunk carries with lam^(8*2^d) multipliers, LDS for the
// 4 wave totals, then per-element fixup with lam^(j+1).
// ---------------------------------------------------------------------------
__global__ __launch_bounds__(256) void k2_scan(float* __restrict__ bure,
                                               float* __restrict__ buim,
                                               const float* __restrict__ lam) {
    int p = blockIdx.x, b = blockIdx.y;
    int t = threadIdx.x;
    float lr = lam[p], li = lam[SSM + p];
    size_t base = ((size_t)(b * SSM + p)) * LEN + t * 8;

    float4 r0 = *(const float4*)&bure[base];
    float4 r1 = *(const float4*)&bure[base + 4];
    float4 i0 = *(const float4*)&buim[base];
    float4 i1 = *(const float4*)&buim[base + 4];
    float br[8] = {r0.x, r0.y, r0.z, r0.w, r1.x, r1.y, r1.z, r1.w};
    float bi[8] = {i0.x, i0.y, i0.z, i0.w, i1.x, i1.y, i1.z, i1.w};

    float xr[8], xi[8];
    float cr = 0.f, ci = 0.f;
#pragma unroll
    for (int j = 0; j < 8; ++j) {
        float nr = fmaf(lr, cr, fmaf(-li, ci, br[j]));
        float ni = fmaf(lr, ci, fmaf(li, cr, bi[j]));
        cr = nr; ci = ni;
        xr[j] = cr; xi[j] = ci;
    }

    // m = lam^8
    float mr = lr, mi = li;
#pragma unroll
    for (int s = 0; s < 3; ++s) { float tm = mr * mr - mi * mi; mi = 2.f * mr * mi; mr = tm; }

    int lane = t & 63, w = t >> 6;
    float plr = 1.f, pli = 0.f;   // accumulates lam^(8*lane)
#pragma unroll
    for (int o = 1; o < 64; o <<= 1) {
        float ur = __shfl_up(cr, (unsigned)o, 64);
        float ui = __shfl_up(ci, (unsigned)o, 64);
        if (lane & o) { float tp = plr * mr - pli * mi; pli = plr * mi + pli * mr; plr = tp; }
        if (lane >= o) {
            cr = fmaf(mr, ur, fmaf(-mi, ui, cr));
            ci = fmaf(mr, ui, fmaf(mi, ur, ci));
        }
        float tm = mr * mr - mi * mi; mi = 2.f * mr * mi; mr = tm;
    }
    // mr,mi = lam^512 now; cr,ci = within-wave inclusive carry scan.
    __shared__ float wtr[4], wti[4];
    if (lane == 63) { wtr[w] = cr; wti[w] = ci; }
    __syncthreads();
    float Pr = 0.f, Pi = 0.f;     // carry entering this wave
    for (int w2 = 0; w2 < w; ++w2) {
        float nr = fmaf(mr, Pr, fmaf(-mi, Pi, wtr[w2]));
        float ni = fmaf(mr, Pi, fmaf(mi, Pr, wti[w2]));
        Pr = nr; Pi = ni;
    }
    float er = __shfl_up(cr, 1u, 64);
    float ei = __shfl_up(ci, 1u, 64);
    if (lane == 0) { er = 0.f; ei = 0.f; }
    // carry entering this thread's chunk:
    float cinr = er + plr * Pr - pli * Pi;
    float cini = ei + plr * Pi + pli * Pr;

    float fr = lr, fi = li;       // lam^(j+1)
#pragma unroll
    for (int j = 0; j < 8; ++j) {
        xr[j] = fmaf(fr, cinr, fmaf(-fi, cini, xr[j]));
        xi[j] = fmaf(fr, cini, fmaf(fi, cinr, xi[j]));
        float nf = fr * lr - fi * li; fi = fr * li + fi * lr; fr = nf;
    }
    *(float4*)&bure[base]     = make_float4(xr[0], xr[1], xr[2], xr[3]);
    *(float4*)&bure[base + 4] = make_float4(xr[4], xr[5], xr[6], xr[7]);
    *(float4*)&buim[base]     = make_float4(xi[0], xi[1], xi[2], xi[3]);
    *(float4*)&buim[base + 4] = make_float4(xi[4], xi[5], xi[6], xi[7]);
}

// ---------------------------------------------------------------------------
// K3: out[b][l][h] = sum_p sre[b][p][l]*C[h][p][0] - sim[b][p][l]*C[h][p][1]
//                    + u[b][l][h]*D[h]
// Tile: 64 l x 128 h per block, K chunks of 32 p. grid (32,32), block 256.
// Thread tile: 4l x 8h.
// ---------------------------------------------------------------------------
__global__ __launch_bounds__(256) void k3_out(const float* __restrict__ sre,
                                              const float* __restrict__ sim,
                                              const float* __restrict__ u,
                                              const float* __restrict__ C,
                                              const float* __restrict__ D,
                                              float* __restrict__ out) {
    __shared__ __align__(16) float sS[2][32][64];   // [comp][p][l]
    __shared__ __align__(16) float sC[2][32][132];  // [comp][p][h] (pad 4)
    int tid = threadIdx.x;
    int l0  = blockIdx.x * 64;
    int b   = blockIdx.y;
    int th  = tid & 15;      // 8 h each
    int tl  = tid >> 4;      // 4 l each

    float acc[4][8];
#pragma unroll
    for (int j = 0; j < 4; ++j)
#pragma unroll
        for (int q = 0; q < 8; ++q) acc[j][q] = 0.f;

    for (int pc = 0; pc < SSM; pc += 32) {
        // stage states: 2 comps x 32p x 64l
#pragma unroll
        for (int i = 0; i < 4; ++i) {
            int idx  = tid + 256 * i;        // 0..1023
            int comp = idx >> 9;             // 0/1
            int pp   = (idx >> 4) & 31;
            int lq   = idx & 15;
            const float* src = comp ? sim : sre;
            float4 v = *(const float4*)&src[((size_t)(b * SSM + pc + pp)) * LEN + l0 + lq * 4];
            *(float4*)&sS[comp][pp][lq * 4] = v;
        }
        // stage C: 128h x 32p both comps (interleaved re/im -> float4 = 2 p)
#pragma unroll
        for (int i = 0; i < 8; ++i) {
            int idx = tid + 256 * i;         // 0..2047
            int h   = idx >> 4;              // 0..127
            int pq  = idx & 15;              // p = pc + 2*pq
            float4 v = *(const float4*)&C[(size_t)(h * SSM + pc + pq * 2) * 2];
            sC[0][pq * 2][h]     = v.x;
            sC[1][pq * 2][h]     = v.y;
            sC[0][pq * 2 + 1][h] = v.z;
            sC[1][pq * 2 + 1][h] = v.w;
        }
        __syncthreads();
#pragma unroll
        for (int p = 0; p < 32; ++p) {
            float4 a0 = *(const float4*)&sS[0][p][tl * 4];
            float4 a1 = *(const float4*)&sS[1][p][tl * 4];
            float4 c0 = *(const float4*)&sC[0][p][th * 8];
            float4 c1 = *(const float4*)&sC[0][p][th * 8 + 4];
            float4 e0 = *(const float4*)&sC[1][p][th * 8];
            float4 e1 = *(const float4*)&sC[1][p][th * 8 + 4];
            float sr[4] = {a0.x, a0.y, a0.z, a0.w};
            float si[4] = {a1.x, a1.y, a1.z, a1.w};
            float cre[8] = {c0.x, c0.y, c0.z, c0.w, c1.x, c1.y, c1.z, c1.w};
            float cim[8] = {e0.x, e0.y, e0.z, e0.w, e1.x, e1.y, e1.z, e1.w};
#pragma unroll
            for (int j = 0; j < 4; ++j)
#pragma unroll
                for (int q = 0; q < 8; ++q)
                    acc[j][q] = fmaf(sr[j], cre[q], fmaf(-si[j], cim[q], acc[j][q]));
        }
        __syncthreads();
    }
    float4 d0 = *(const float4*)&D[th * 8];
    float4 d1 = *(const float4*)&D[th * 8 + 4];
    float dd[8] = {d0.x, d0.y, d0.z, d0.w, d1.x, d1.y, d1.z, d1.w};
#pragma unroll
    for (int j = 0; j < 4; ++j) {
        size_t row = ((size_t)b * LEN + l0 + tl * 4 + j) * HID + th * 8;
        float4 u0 = *(const float4*)&u[row];
        float4 u1 = *(const float4*)&u[row + 4];
        float uu[8] = {u0.x, u0.y, u0.z, u0.w, u1.x, u1.y, u1.z, u1.w};
        float o[8];
#pragma unroll
        for (int q = 0; q < 8; ++q) o[q] = fmaf(uu[q], dd[q], acc[j][q]);
        *(float4*)&out[row]     = make_float4(o[0], o[1], o[2], o[3]);
        *(float4*)&out[row + 4] = make_float4(o[4], o[5], o[6], o[7]);
    }
}

// ---------------------------------------------------------------------------
// Workspace layout (floats):
//   [0, 16777216)            bu_re / states_re  [32][256][2048]
//   [16777216, 33554432)     bu_im / states_im
//   [33554432, 33554944)     lam (re 256, im 256)
// Total ~134.2 MB.
// ---------------------------------------------------------------------------
extern "C" void kernel_launch(void* const* d_in, const int* in_sizes, int n_in,
                              void* d_out, int out_size, void* d_ws, size_t ws_size,
                              hipStream_t stream) {
    const float* u  = (const float*)d_in[0];
    const float* A  = (const float*)d_in[1];
    const float* G  = (const float*)d_in[2];
    const float* st = (const float*)d_in[3];
    const float* B  = (const float*)d_in[4];
    const float* C  = (const float*)d_in[5];
    const float* D  = (const float*)d_in[6];
    float* out = (float*)d_out;

    float* W    = (float*)d_ws;
    float* bure = W;
    float* buim = W + (size_t)16777216;
    float* lam  = W + (size_t)33554432;

    k0_params<<<1, 256, 0, stream>>>(A, G, st, lam);
    k1_bu<<<dim3(16, 4, 32), 256, 0, stream>>>(u, B, bure, buim);
    k2_scan<<<dim3(256, 32), 256, 0, stream>>>(bure, buim, lam);
    k3_out<<<dim3(32, 32), 256, 0, stream>>>(bure, buim, u, C, D, out);
}

// Round 2
// 160.815 us; speedup vs baseline: 1.7587x; 1.7587x over previous
//
#include <hip/hip_runtime.h>
#include <math.h>

#define BATCH 32
#define LEN   2048
#define HID   128
#define SSM   256

static const size_t PLz = 16777216;   // elements per bu/state plane (32*256*2048)
#define BPL 32768                     // elements per B-split plane (256*128)
#define CPL 32768                     // elements per C-split plane (128*256)

typedef __attribute__((ext_vector_type(4))) float f32x4;
typedef __attribute__((ext_vector_type(8))) short bf16x8;
typedef __attribute__((ext_vector_type(4))) short bf16x4;
typedef __attribute__((ext_vector_type(4))) int   i32x4;

// f32 -> bf16 round-to-nearest-even (bit trick, valid for finite values)
static __device__ __forceinline__ unsigned short f2bf(float x) {
    union { float f; unsigned u; } v; v.f = x;
    unsigned r = (v.u + 0x7FFFu + ((v.u >> 16) & 1u)) >> 16;
    return (unsigned short)r;
}
static __device__ __forceinline__ float bf2f(unsigned short b) {
    union { unsigned u; float f; } v; v.u = ((unsigned)b) << 16;
    return v.f;
}

// ---------------------------------------------------------------------------
// K0: parameter projection + eigenvalue. lam[0..255]=re, lam[256..511]=im.
// ---------------------------------------------------------------------------
__global__ void k0_params(const float* __restrict__ A, const float* __restrict__ G,
                          const float* __restrict__ steps, float* __restrict__ lam) {
    int p = threadIdx.x;
    if (p < SSM) {
        float stp   = 1.f / (1.f + expf(-steps[p]));
        float g     = fmaxf(G[p], 0.f);
        float denom = fmaxf(stp * stp, 1e-6f);
        float s     = stp * g;
        float base  = sqrtf(fmaxf(1.f + s, 1e-6f));
        float alow  = (2.f + s - 2.f * base) / denom;
        float ahigh = (2.f + s + 2.f * base) / denom;
        float a     = alow + fmaxf(A[p] - alow, 0.f) - fmaxf(A[p] - ahigh, 0.f);
        float S     = 1.f / (1.f + stp * g);
        float T     = S + 1.f - stp * stp * S * a;
        lam[p]       = 0.5f * T;
        lam[SSM + p] = sqrtf(fmaxf(S - 0.25f * T * T, 0.f));
    }
}

// ---------------------------------------------------------------------------
// K0b: pre-split B and C into hi/lo bf16 planes.
// Bsp planes: [re_hi, re_lo, im_hi, im_lo], layout [p][h] (p*128+h)
// Csp planes: [re_hi, re_lo, nim_hi, nim_lo] (imag NEGATED), layout [h][p]
// ---------------------------------------------------------------------------
__global__ __launch_bounds__(256) void k0b_prep(const float* __restrict__ Bm,
                                                const float* __restrict__ Cm,
                                                unsigned short* __restrict__ Bsp,
                                                unsigned short* __restrict__ Csp) {
    int gidx = blockIdx.x * 256 + threadIdx.x;
    if (gidx < 32768) {
        int p = gidx >> 7, h = gidx & 127;
        float vr = Bm[(size_t)(p * HID + h) * 2];
        float vi = Bm[(size_t)(p * HID + h) * 2 + 1];
        unsigned short hh = f2bf(vr);
        Bsp[0 * BPL + p * HID + h] = hh;
        Bsp[1 * BPL + p * HID + h] = f2bf(vr - bf2f(hh));
        hh = f2bf(vi);
        Bsp[2 * BPL + p * HID + h] = hh;
        Bsp[3 * BPL + p * HID + h] = f2bf(vi - bf2f(hh));
    } else {
        int g2 = gidx - 32768;
        int h = g2 >> 8, p = g2 & 255;
        float vr = Cm[(size_t)(h * SSM + p) * 2];
        float vi = -Cm[(size_t)(h * SSM + p) * 2 + 1];
        unsigned short hh = f2bf(vr);
        Csp[0 * CPL + h * SSM + p] = hh;
        Csp[1 * CPL + h * SSM + p] = f2bf(vr - bf2f(hh));
        hh = f2bf(vi);
        Csp[2 * CPL + h * SSM + p] = hh;
        Csp[3 * CPL + h * SSM + p] = f2bf(vi - bf2f(hh));
    }
}

// ---------------------------------------------------------------------------
// K1 (MFMA): bu[b][p][l] = sum_h u[b][l][h] * B[p][h][{re,im}]
// M=l (tile 128), N=p (tile 64), K=h=128 in BK=32 chunks. 4 waves (2l x 2p),
// wave tile 64l x 32p. Split-bf16: 3 MFMAs per product.
// Output written as 4 bf16 planes (re_hi, re_lo, im_hi, im_lo), [b][p][l].
// ---------------------------------------------------------------------------
__global__ __launch_bounds__(256) void k1_bu(const float* __restrict__ u,
                                             const unsigned short* __restrict__ Bsp,
                                             unsigned short* __restrict__ planes) {
    __shared__ __align__(16) unsigned short sU[2][128][40];
    __shared__ __align__(16) unsigned short sB[4][64][40];
    int tid = threadIdx.x;
    int l0 = blockIdx.x * 128, p0 = blockIdx.y * 64, b = blockIdx.z;
    int lane = tid & 63, w = tid >> 6;
    int wl = w >> 1, wp = w & 1;
    int fr = lane & 15, g = lane >> 4;

    f32x4 accr[4][2], acci[4][2];
#pragma unroll
    for (int mi = 0; mi < 4; ++mi)
#pragma unroll
        for (int ni = 0; ni < 2; ++ni) {
            accr[mi][ni] = (f32x4)(0.f);
            acci[mi][ni] = (f32x4)(0.f);
        }

    for (int kc = 0; kc < HID; kc += 32) {
        // stage u tile [128 l][32 h] -> hi/lo planes
        {
            int hq = tid & 7;
#pragma unroll
            for (int r = 0; r < 4; ++r) {
                int l = (tid >> 3) + 32 * r;
                f32x4 v = *(const f32x4*)&u[((size_t)b * LEN + l0 + l) * HID + kc + hq * 4];
                bf16x4 hv, lv;
#pragma unroll
                for (int e = 0; e < 4; ++e) {
                    unsigned short hh = f2bf(v[e]);
                    hv[e] = (short)hh;
                    lv[e] = (short)f2bf(v[e] - bf2f(hh));
                }
                *(bf16x4*)&sU[0][l][hq * 4] = hv;
                *(bf16x4*)&sU[1][l][hq * 4] = lv;
            }
        }
        // stage B planes [64 p][32 h]
        {
            int p_ = tid >> 2, hoct = tid & 3;
#pragma unroll
            for (int pl = 0; pl < 4; ++pl) {
                i32x4 v = *(const i32x4*)&Bsp[(size_t)pl * BPL + (size_t)(p0 + p_) * HID + kc + hoct * 8];
                *(i32x4*)&sB[pl][p_][hoct * 8] = v;
            }
        }
        __syncthreads();

        int kk = g * 8;
        bf16x8 brh[2], brl[2], bih[2], bil[2];
#pragma unroll
        for (int ni = 0; ni < 2; ++ni) {
            int pr = wp * 32 + ni * 16 + fr;
            brh[ni] = *(const bf16x8*)&sB[0][pr][kk];
            brl[ni] = *(const bf16x8*)&sB[1][pr][kk];
            bih[ni] = *(const bf16x8*)&sB[2][pr][kk];
            bil[ni] = *(const bf16x8*)&sB[3][pr][kk];
        }
#pragma unroll
        for (int mi = 0; mi < 4; ++mi) {
            int lr_ = wl * 64 + mi * 16 + fr;
            bf16x8 ah = *(const bf16x8*)&sU[0][lr_][kk];
            bf16x8 al = *(const bf16x8*)&sU[1][lr_][kk];
#pragma unroll
            for (int ni = 0; ni < 2; ++ni) {
                accr[mi][ni] = __builtin_amdgcn_mfma_f32_16x16x32_bf16(ah, brh[ni], accr[mi][ni], 0, 0, 0);
                accr[mi][ni] = __builtin_amdgcn_mfma_f32_16x16x32_bf16(ah, brl[ni], accr[mi][ni], 0, 0, 0);
                accr[mi][ni] = __builtin_amdgcn_mfma_f32_16x16x32_bf16(al, brh[ni], accr[mi][ni], 0, 0, 0);
                acci[mi][ni] = __builtin_amdgcn_mfma_f32_16x16x32_bf16(ah, bih[ni], acci[mi][ni], 0, 0, 0);
                acci[mi][ni] = __builtin_amdgcn_mfma_f32_16x16x32_bf16(ah, bil[ni], acci[mi][ni], 0, 0, 0);
                acci[mi][ni] = __builtin_amdgcn_mfma_f32_16x16x32_bf16(al, bih[ni], acci[mi][ni], 0, 0, 0);
            }
        }
        __syncthreads();
    }

    // epilogue: split acc into hi/lo bf16 planes; C/D map: col=lane&15 (p), row=g*4+r (l)
#pragma unroll
    for (int mi = 0; mi < 4; ++mi)
#pragma unroll
        for (int ni = 0; ni < 2; ++ni) {
            int pcol = p0 + wp * 32 + ni * 16 + fr;
            int lrow = l0 + wl * 64 + mi * 16 + g * 4;
            size_t idx = ((size_t)(b * SSM + pcol)) * LEN + lrow;
            f32x4 vr = accr[mi][ni], vi = acci[mi][ni];
            bf16x4 rh, rl, ih, il;
#pragma unroll
            for (int e = 0; e < 4; ++e) {
                unsigned short hh = f2bf(vr[e]);
                rh[e] = (short)hh; rl[e] = (short)f2bf(vr[e] - bf2f(hh));
                hh = f2bf(vi[e]);
                ih[e] = (short)hh; il[e] = (short)f2bf(vi[e] - bf2f(hh));
            }
            *(bf16x4*)&planes[0 * PLz + idx] = rh;
            *(bf16x4*)&planes[1 * PLz + idx] = rl;
            *(bf16x4*)&planes[2 * PLz + idx] = ih;
            *(bf16x4*)&planes[3 * PLz + idx] = il;
        }
}

// ---------------------------------------------------------------------------
// K2: in-place inclusive scan x_k = lam*x_{k-1} + bu_k along l for each (b,p).
// Reads/writes the 4 bf16 hi/lo planes; scan math in f32 (identical to the
// verified round-1 kernel).
// ---------------------------------------------------------------------------
__global__ __launch_bounds__(256) void k2_scan(unsigned short* __restrict__ planes,
                                               const float* __restrict__ lam) {
    int p = blockIdx.x, b = blockIdx.y;
    int t = threadIdx.x;
    float lr = lam[p], li = lam[SSM + p];
    size_t base = ((size_t)(b * SSM + p)) * LEN + t * 8;

    bf16x8 vrh = *(const bf16x8*)&planes[0 * PLz + base];
    bf16x8 vrl = *(const bf16x8*)&planes[1 * PLz + base];
    bf16x8 vih = *(const bf16x8*)&planes[2 * PLz + base];
    bf16x8 vil = *(const bf16x8*)&planes[3 * PLz + base];
    float br[8], bi[8];
#pragma unroll
    for (int j = 0; j < 8; ++j) {
        br[j] = bf2f((unsigned short)vrh[j]) + bf2f((unsigned short)vrl[j]);
        bi[j] = bf2f((unsigned short)vih[j]) + bf2f((unsigned short)vil[j]);
    }

    float xr[8], xi[8];
    float cr = 0.f, ci = 0.f;
#pragma unroll
    for (int j = 0; j < 8; ++j) {
        float nr = fmaf(lr, cr, fmaf(-li, ci, br[j]));
        float ni = fmaf(lr, ci, fmaf(li, cr, bi[j]));
        cr = nr; ci = ni;
        xr[j] = cr; xi[j] = ci;
    }

    float mr = lr, mi = li;
#pragma unroll
    for (int s = 0; s < 3; ++s) { float tm = mr * mr - mi * mi; mi = 2.f * mr * mi; mr = tm; }

    int lane = t & 63, w = t >> 6;
    float plr = 1.f, pli = 0.f;
#pragma unroll
    for (int o = 1; o < 64; o <<= 1) {
        float ur = __shfl_up(cr, (unsigned)o, 64);
        float ui = __shfl_up(ci, (unsigned)o, 64);
        if (lane & o) { float tp = plr * mr - pli * mi; pli = plr * mi + pli * mr; plr = tp; }
        if (lane >= o) {
            cr = fmaf(mr, ur, fmaf(-mi, ui, cr));
            ci = fmaf(mr, ui, fmaf(mi, ur, ci));
        }
        float tm = mr * mr - mi * mi; mi = 2.f * mr * mi; mr = tm;
    }
    __shared__ float wtr[4], wti[4];
    if (lane == 63) { wtr[w] = cr; wti[w] = ci; }
    __syncthreads();
    float Pr = 0.f, Pi = 0.f;
    for (int w2 = 0; w2 < w; ++w2) {
        float nr = fmaf(mr, Pr, fmaf(-mi, Pi, wtr[w2]));
        float ni = fmaf(mr, Pi, fmaf(mi, Pr, wti[w2]));
        Pr = nr; Pi = ni;
    }
    float er = __shfl_up(cr, 1u, 64);
    float ei = __shfl_up(ci, 1u, 64);
    if (lane == 0) { er = 0.f; ei = 0.f; }
    float cinr = er + plr * Pr - pli * Pi;
    float cini = ei + plr * Pi + pli * Pr;

    float fr = lr, fi = li;
#pragma unroll
    for (int j = 0; j < 8; ++j) {
        xr[j] = fmaf(fr, cinr, fmaf(-fi, cini, xr[j]));
        xi[j] = fmaf(fr, cini, fmaf(fi, cinr, xi[j]));
        float nf = fr * lr - fi * li; fi = fr * li + fi * lr; fr = nf;
    }

    bf16x8 orh, orl, oih, oil;
#pragma unroll
    for (int j = 0; j < 8; ++j) {
        unsigned short hh = f2bf(xr[j]);
        orh[j] = (short)hh; orl[j] = (short)f2bf(xr[j] - bf2f(hh));
        hh = f2bf(xi[j]);
        oih[j] = (short)hh; oil[j] = (short)f2bf(xi[j] - bf2f(hh));
    }
    *(bf16x8*)&planes[0 * PLz + base] = orh;
    *(bf16x8*)&planes[1 * PLz + base] = orl;
    *(bf16x8*)&planes[2 * PLz + base] = oih;
    *(bf16x8*)&planes[3 * PLz + base] = oil;
}

// ---------------------------------------------------------------------------
// K3 (MFMA): out[b][l][h] = sum_p s_re*C_re - s_im*C_im + u*D
// M=l (tile 128), N=h (128, full), K=p=256 in BK=32 chunks. 4 waves (2l x 2h),
// wave tile 64l x 64h. A (states) staged transposed [l][p] via rotated-order
// ds_write_b16 (bank-spread); B (C-matrix planes, imag pre-negated) staged
// straight [h][p]. Split-bf16: 6 MFMAs per (mi,ni) per chunk.
// ---------------------------------------------------------------------------
__global__ __launch_bounds__(256) void k3_out(const unsigned short* __restrict__ planes,
                                              const unsigned short* __restrict__ Csp,
                                              const float* __restrict__ u,
                                              const float* __restrict__ D,
                                              float* __restrict__ out) {
    __shared__ __align__(16) unsigned short sA[4][128][40];
    __shared__ __align__(16) unsigned short sC[4][128][40];
    int tid = threadIdx.x;
    int l0 = blockIdx.x * 128, b = blockIdx.y;
    int lane = tid & 63, w = tid >> 6;
    int wl = w >> 1, wh = w & 1;
    int fr = lane & 15, g = lane >> 4;

    f32x4 acc[4][4];
#pragma unroll
    for (int mi = 0; mi < 4; ++mi)
#pragma unroll
        for (int ni = 0; ni < 4; ++ni) acc[mi][ni] = (f32x4)(0.f);

    float dv[4];
#pragma unroll
    for (int ni = 0; ni < 4; ++ni) dv[ni] = D[wh * 64 + ni * 16 + fr];

    for (int pc = 0; pc < SSM; pc += 32) {
        // ---- stage A (states planes), transposed to [l][p] ----
        {
            int loct = tid & 15;
#pragma unroll
            for (int r = 0; r < 2; ++r) {
                int p_ = (tid >> 4) + 16 * r;
                int rot = (loct + p_) & 7;
#pragma unroll
                for (int pl = 0; pl < 4; ++pl) {
                    union { bf16x8 v; unsigned long long q[2]; } U;
                    U.v = *(const bf16x8*)&planes[(size_t)pl * PLz +
                            ((size_t)(b * SSM + pc + p_)) * LEN + l0 + loct * 8];
                    unsigned long long x0 = U.q[0], x1 = U.q[1];
                    // rotate-right by rot 16-bit elements, constant-shift stages
                    if (rot & 4) { unsigned long long tq = x0; x0 = x1; x1 = tq; }
                    if (rot & 2) {
                        unsigned long long n0 = (x0 >> 32) | (x1 << 32);
                        unsigned long long n1 = (x1 >> 32) | (x0 << 32);
                        x0 = n0; x1 = n1;
                    }
                    if (rot & 1) {
                        unsigned long long n0 = (x0 >> 16) | (x1 << 48);
                        unsigned long long n1 = (x1 >> 16) | (x0 << 48);
                        x0 = n0; x1 = n1;
                    }
                    int rb = loct * 8;
                    sA[pl][rb + ((0 + rot) & 7)][p_] = (unsigned short)(x0);
                    sA[pl][rb + ((1 + rot) & 7)][p_] = (unsigned short)(x0 >> 16);
                    sA[pl][rb + ((2 + rot) & 7)][p_] = (unsigned short)(x0 >> 32);
                    sA[pl][rb + ((3 + rot) & 7)][p_] = (unsigned short)(x0 >> 48);
                    sA[pl][rb + ((4 + rot) & 7)][p_] = (unsigned short)(x1);
                    sA[pl][rb + ((5 + rot) & 7)][p_] = (unsigned short)(x1 >> 16);
                    sA[pl][rb + ((6 + rot) & 7)][p_] = (unsigned short)(x1 >> 32);
                    sA[pl][rb + ((7 + rot) & 7)][p_] = (unsigned short)(x1 >> 48);
                }
            }
        }
        // ---- stage C planes [128 h][32 p] ----
        {
            int poct = tid & 3;
#pragma unroll
            for (int r2 = 0; r2 < 2; ++r2) {
                int hh = (tid >> 2) + 64 * r2;
#pragma unroll
                for (int pl = 0; pl < 4; ++pl) {
                    i32x4 v = *(const i32x4*)&Csp[(size_t)pl * CPL + (size_t)hh * SSM + pc + poct * 8];
                    *(i32x4*)&sC[pl][hh][poct * 8] = v;
                }
            }
        }
        __syncthreads();

        int kk = g * 8;
        bf16x8 crh[4], crl[4], cih[4], cil[4];
#pragma unroll
        for (int ni = 0; ni < 4; ++ni) {
            int hr = wh * 64 + ni * 16 + fr;
            crh[ni] = *(const bf16x8*)&sC[0][hr][kk];
            crl[ni] = *(const bf16x8*)&sC[1][hr][kk];
            cih[ni] = *(const bf16x8*)&sC[2][hr][kk];
            cil[ni] = *(const bf16x8*)&sC[3][hr][kk];
        }
#pragma unroll
        for (int mi = 0; mi < 4; ++mi) {
            int lr_ = wl * 64 + mi * 16 + fr;
            bf16x8 arh = *(const bf16x8*)&sA[0][lr_][kk];
            bf16x8 arl = *(const bf16x8*)&sA[1][lr_][kk];
            bf16x8 aih = *(const bf16x8*)&sA[2][lr_][kk];
            bf16x8 ail = *(const bf16x8*)&sA[3][lr_][kk];
#pragma unroll
            for (int ni = 0; ni < 4; ++ni) {
                acc[mi][ni] = __builtin_amdgcn_mfma_f32_16x16x32_bf16(arh, crh[ni], acc[mi][ni], 0, 0, 0);
                acc[mi][ni] = __builtin_amdgcn_mfma_f32_16x16x32_bf16(arh, crl[ni], acc[mi][ni], 0, 0, 0);
                acc[mi][ni] = __builtin_amdgcn_mfma_f32_16x16x32_bf16(arl, crh[ni], acc[mi][ni], 0, 0, 0);
                acc[mi][ni] = __builtin_amdgcn_mfma_f32_16x16x32_bf16(aih, cih[ni], acc[mi][ni], 0, 0, 0);
                acc[mi][ni] = __builtin_amdgcn_mfma_f32_16x16x32_bf16(aih, cil[ni], acc[mi][ni], 0, 0, 0);
                acc[mi][ni] = __builtin_amdgcn_mfma_f32_16x16x32_bf16(ail, cih[ni], acc[mi][ni], 0, 0, 0);
            }
        }
        __syncthreads();
    }

    // epilogue: out = acc + u*D ; C/D map: col=lane&15 (h), row=g*4+r (l)
#pragma unroll
    for (int mi = 0; mi < 4; ++mi)
#pragma unroll
        for (int ni = 0; ni < 4; ++ni) {
            int lb = l0 + wl * 64 + mi * 16 + g * 4;
            int h = wh * 64 + ni * 16 + fr;
#pragma unroll
            for (int r = 0; r < 4; ++r) {
                size_t idx = ((size_t)b * LEN + lb + r) * HID + h;
                out[idx] = acc[mi][ni][r] + u[idx] * dv[ni];
            }
        }
}

// ---------------------------------------------------------------------------
// Workspace layout (bytes):
//   [0, 134217728)             4 bf16 planes (bu then states, in-place)
//   [134217728, 134219776)     lam (512 f32)
//   [134219776, 134481920)     B split planes (4 x 32768 ushort)
//   [134481920, 134744064)     C split planes (4 x 32768 ushort)
// ---------------------------------------------------------------------------
extern "C" void kernel_launch(void* const* d_in, const int* in_sizes, int n_in,
                              void* d_out, int out_size, void* d_ws, size_t ws_size,
                              hipStream_t stream) {
    const float* u  = (const float*)d_in[0];
    const float* A  = (const float*)d_in[1];
    const float* G  = (const float*)d_in[2];
    const float* st = (const float*)d_in[3];
    const float* B  = (const float*)d_in[4];
    const float* C  = (const float*)d_in[5];
    const float* D  = (const float*)d_in[6];
    float* out = (float*)d_out;

    char* WS = (char*)d_ws;
    unsigned short* planes = (unsigned short*)WS;
    float* lam             = (float*)(WS + 134217728);
    unsigned short* Bsp    = (unsigned short*)(WS + 134219776);
    unsigned short* Csp    = (unsigned short*)(WS + 134481920);

    k0_params<<<1, 256, 0, stream>>>(A, G, st, lam);
    k0b_prep<<<256, 256, 0, stream>>>(B, C, Bsp, Csp);
    k1_bu<<<dim3(16, 4, 32), 256, 0, stream>>>(u, Bsp, planes);
    k2_scan<<<dim3(256, 32), 256, 0, stream>>>(planes, lam);
    k3_out<<<dim3(16, 32), 256, 0, stream>>>(planes, Csp, u, D, out);
}